// Round 1
// baseline (163.651 us; speedup 1.0000x reference)
//
#include <hip/hip_runtime.h>

typedef __attribute__((ext_vector_type(8))) short    bf16x8;
typedef __attribute__((ext_vector_type(4))) float    f32x4;
typedef __attribute__((ext_vector_type(4))) float    float4_t;
typedef __attribute__((ext_vector_type(4))) unsigned u32x4;
typedef __attribute__((ext_vector_type(2))) unsigned u32x2;

constexpr int NSAMP    = 32768;
constexpr int INSZ     = 255;
constexpr int DIM      = 256;     // IN_SIZE + bias
constexpr int NSPLIT   = 1023;
constexpr int BM       = 64;      // samples per block
constexpr int NTHREADS = 256;     // 4 waves

// LDS layout (dynamic, 160 KiB total):
//  [0, 32768)        : phase 1 = x tile bf16 [64][256], swizzled byte ^= (row&7)<<4
//                      phase 2 = Wz staged f32[2048], Wzs[i] = W[256+i-1] (i>=1)
//  [32768, 163840)   : XA tile bf16 [64 rows][1024 pos], pos = split_id+1, pos 0 = x.Wx
//                      within-row byte offset ^= ((row>>2)&3)<<3
constexpr int XA_OFF    = 32768;
constexpr int LDS_BYTES = 32768 + BM * 2048;   // 163840

extern __shared__ char smem[];

__device__ __forceinline__ short f2bf(float f) {
  unsigned x = __builtin_bit_cast(unsigned, f);
  x += 0x7fffu + ((x >> 16) & 1u);            // RNE
  return (short)(x >> 16);
}
__device__ __forceinline__ float bfraw(unsigned hw16) {
  return __builtin_bit_cast(float, hw16 << 16);
}
__device__ __forceinline__ unsigned cvt_pk(float lo, float hi) {
  unsigned r;
  asm("v_cvt_pk_bf16_f32 %0, %1, %2" : "=v"(r) : "v"(lo), "v"(hi));
  return r;
}
__device__ __forceinline__ float clamp01(float v) {
  return fminf(fmaxf(v, 0.f), 1.f);
}

__global__ __launch_bounds__(NTHREADS, 1)
void lt_fused(const float* __restrict__ X, const float* __restrict__ A,
              const float* __restrict__ W, const float* __restrict__ Bv,
              float* __restrict__ Out)
{
  const int tid  = threadIdx.x;
  const int lane = tid & 63;
  const int wave = tid >> 6;
  const int m0   = blockIdx.x * BM;

  // ---------------- stage x tile (f32 global -> bf16 LDS, swizzled) ----------------
  for (int idx = tid; idx < BM * DIM; idx += NTHREADS) {
    int row = idx >> 8, col = idx & 255;
    float v = (col < INSZ) ? X[(m0 + row) * INSZ + col] : 1.0f;   // bias column
    int byt = ((row << 9) + (col << 1)) ^ ((row & 7) << 4);
    *(short*)(smem + byt) = f2bf(v);
  }
  __syncthreads();

  // ---------------- phase 1: XA = x @ A^T via MFMA (bf16) ----------------
  // preload x fragments: 4 M-tiles x 8 K-steps, 8 consecutive bf16 per lane
  bf16x8 xf[4][8];
#pragma unroll
  for (int mt = 0; mt < 4; ++mt) {
    int row = mt * 16 + (lane & 15);
#pragma unroll
    for (int ks = 0; ks < 8; ++ks) {
      int kk  = ks * 32 + ((lane >> 4) << 3);
      int byt = ((row << 9) + (kk << 1)) ^ ((row & 7) << 4);
      xf[mt][ks] = *(const bf16x8*)(smem + byt);
    }
  }

  const int ncb = wave * 256 + (lane & 15);     // this lane's node column base
  const int kk0 = (lane >> 4) << 3;
  for (int nt = 0; nt < 16; ++nt) {
    int col = ncb + nt * 16;                     // 0..1023
    // col 1023 is not a real split node: reuse it to compute x . Wx (stored at pos 0)
    const float* ap = (col < NSPLIT) ? (A + col * DIM) : W;
    int pos = (col < NSPLIT) ? (col + 1) : 0;

    bf16x8 bfr[8];
#pragma unroll
    for (int ks = 0; ks < 8; ++ks) {
      float4_t a0 = *(const float4_t*)(ap + ks * 32 + kk0);
      float4_t a1 = *(const float4_t*)(ap + ks * 32 + kk0 + 4);
      u32x4 p;
      p[0] = cvt_pk(a0[0], a0[1]);
      p[1] = cvt_pk(a0[2], a0[3]);
      p[2] = cvt_pk(a1[0], a1[1]);
      p[3] = cvt_pk(a1[2], a1[3]);
      bfr[ks] = __builtin_bit_cast(bf16x8, p);
    }

#pragma unroll
    for (int mt = 0; mt < 4; ++mt) {
      f32x4 acc = {0.f, 0.f, 0.f, 0.f};
#pragma unroll
      for (int ks = 0; ks < 8; ++ks)
        acc = __builtin_amdgcn_mfma_f32_16x16x32_bf16(xf[mt][ks], bfr[ks], acc, 0, 0, 0);
      // C/D layout: col = lane&15 (node), row = (lane>>4)*4 + j (sample)
#pragma unroll
      for (int j = 0; j < 4; ++j) {
        int row = mt * 16 + ((lane >> 4) << 2) + j;
        int byt = XA_OFF + (row << 11) + (((pos << 1)) ^ (((row >> 2) & 3) << 3));
        *(short*)(smem + byt) = f2bf(acc[j]);
      }
    }
  }
  __syncthreads();

  // ---------------- stage Wz (shifted by +1 for alignment) into dead x-tile region ----------------
  for (int i = tid; i < 2048; i += NTHREADS) {
    float w = (i > 0) ? W[DIM + i - 1] : 0.f;
    *(float*)(smem + (i << 2)) = w;
  }
  __syncthreads();

  // ---------------- phase 2: tree walk + logistic, 16 samples per wave ----------------
  const float bias = Bv[0] + W[DIM];   // b + root node (z0 = 1) * Wz[0]
  const float* wz  = (const float*)smem;

  for (int t = 0; t < 16; ++t) {
    int r = wave * 16 + t;
    const char* xar = smem + XA_OFF + (r << 11);
    const int   swz = ((r >> 2) & 3) << 3;

    float acc = 0.f;
    float q   = 1.0f;
    // levels 1..6: one node per lane (i = lane), parent q via shuffle
#pragma unroll
    for (int l = 1; l <= 6; ++l) {
      float qp = __shfl(q, lane >> 1, 64);
      int  pos = (1 << (l - 1)) + (lane >> 1);           // split_id + 1
      unsigned hw = *(const unsigned short*)(xar + (((pos << 1)) ^ swz));
      float xa = bfraw(hw);
      float e  = (lane & 1) ? -xa : xa;
      q = fminf(qp, e);
      if (lane < (1 << l))
        acc += clamp01(q) * wz[(1 << l) + lane];
    }
    // level 7: i = 2*lane + {0,1}; parent split id 63+lane -> pos 64+lane
    unsigned h7 = *(const unsigned short*)(xar + ((((64 + lane) << 1)) ^ swz));
    float xa7 = bfraw(h7);
    float q7a = fminf(q, xa7), q7b = fminf(q, -xa7);
    acc += clamp01(q7a) * wz[128 + 2 * lane]
         + clamp01(q7b) * wz[128 + 2 * lane + 1];
    // level 8: i = 4*lane + c; xa pos 128+2*lane+{0,1}
    unsigned u8 = *(const unsigned*)(xar + (((256 + 4 * lane)) ^ swz));
    float x8a = bfraw(u8 & 0xffffu), x8b = bfraw(u8 >> 16);
    float q8[4];
    q8[0] = fminf(q7a, x8a);  q8[1] = fminf(q7a, -x8a);
    q8[2] = fminf(q7b, x8b);  q8[3] = fminf(q7b, -x8b);
    {
      float4_t w8 = *(const float4_t*)(wz + 256 + 4 * lane);
      acc += clamp01(q8[0]) * w8[0] + clamp01(q8[1]) * w8[1]
           + clamp01(q8[2]) * w8[2] + clamp01(q8[3]) * w8[3];
    }
    // level 9: i = 8*lane + c; xa pos 256+4*lane+{0..3}
    u32x2 u9 = *(const u32x2*)(xar + (((512 + 8 * lane)) ^ swz));
    float x9[4] = { bfraw(u9[0] & 0xffffu), bfraw(u9[0] >> 16),
                    bfraw(u9[1] & 0xffffu), bfraw(u9[1] >> 16) };
    float q9[8];
#pragma unroll
    for (int c = 0; c < 8; ++c)
      q9[c] = fminf(q8[c >> 1], (c & 1) ? -x9[c >> 1] : x9[c >> 1]);
    {
      float4_t w9a = *(const float4_t*)(wz + 512 + 8 * lane);
      float4_t w9b = *(const float4_t*)(wz + 512 + 8 * lane + 4);
#pragma unroll
      for (int c = 0; c < 4; ++c) acc += clamp01(q9[c]) * w9a[c];
#pragma unroll
      for (int c = 0; c < 4; ++c) acc += clamp01(q9[4 + c]) * w9b[c];
    }
    // level 10: i = 16*lane + c; xa pos 512+8*lane+{0..7}
    u32x2 uA = *(const u32x2*)(xar + (((1024 + 16 * lane)) ^ swz));
    u32x2 uB = *(const u32x2*)(xar + (((1024 + 16 * lane + 8)) ^ swz));
    float xA[8] = { bfraw(uA[0] & 0xffffu), bfraw(uA[0] >> 16),
                    bfraw(uA[1] & 0xffffu), bfraw(uA[1] >> 16),
                    bfraw(uB[0] & 0xffffu), bfraw(uB[0] >> 16),
                    bfraw(uB[1] & 0xffffu), bfraw(uB[1] >> 16) };
    {
      float4_t wA0 = *(const float4_t*)(wz + 1024 + 16 * lane);
      float4_t wA1 = *(const float4_t*)(wz + 1024 + 16 * lane + 4);
      float4_t wA2 = *(const float4_t*)(wz + 1024 + 16 * lane + 8);
      float4_t wA3 = *(const float4_t*)(wz + 1024 + 16 * lane + 12);
#pragma unroll
      for (int c = 0; c < 16; ++c) {
        float qv = fminf(q9[c >> 1], (c & 1) ? -xA[c >> 1] : xA[c >> 1]);
        float wv = (c < 4) ? wA0[c] : (c < 8) ? wA1[c - 4] : (c < 12) ? wA2[c - 8] : wA3[c - 12];
        acc += clamp01(qv) * wv;
      }
    }
    // x . Wx was computed by MFMA into pos 0
    float xw = bfraw(*(const unsigned short*)(xar + (0 ^ swz)));
    // wave reduction
#pragma unroll
    for (int o = 32; o > 0; o >>= 1) acc += __shfl_xor(acc, o, 64);
    if (lane == 0)
      Out[m0 + r] = 1.f / (1.f + __expf(-(acc + xw + bias)));
  }
}

extern "C" void kernel_launch(void* const* d_in, const int* in_sizes, int n_in,
                              void* d_out, int out_size, void* d_ws, size_t ws_size,
                              hipStream_t stream) {
  (void)in_sizes; (void)n_in; (void)d_ws; (void)ws_size; (void)out_size;
  const float* X  = (const float*)d_in[0];
  const float* A  = (const float*)d_in[1];
  const float* W  = (const float*)d_in[2];
  const float* Bv = (const float*)d_in[3];
  float* Out = (float*)d_out;

  hipFuncSetAttribute(reinterpret_cast<const void*>(lt_fused),
                      hipFuncAttributeMaxDynamicSharedMemorySize, LDS_BYTES);
  lt_fused<<<NSAMP / BM, NTHREADS, LDS_BYTES, stream>>>(X, A, W, Bv, Out);
}

// Round 3
// 75.613 us; speedup vs baseline: 2.1643x; 2.1643x over previous
//
#include <hip/hip_runtime.h>

typedef __attribute__((ext_vector_type(8))) short    bf16x8;
typedef __attribute__((ext_vector_type(4))) float    f32x4;
typedef __attribute__((ext_vector_type(4))) float    float4_t;
typedef __attribute__((ext_vector_type(4))) unsigned u32x4;
typedef __attribute__((ext_vector_type(2))) unsigned u32x2;

constexpr int NSAMP    = 32768;
constexpr int INSZ     = 255;
constexpr int DIM      = 256;      // IN_SIZE + bias
constexpr int NSPLIT   = 1023;
constexpr int NCOL     = 1024;     // 1023 split cols + W as col 1023
constexpr int BM       = 64;       // samples per block
constexpr int NTHREADS = 512;      // 8 waves

// LDS layout (round-1 verified):
//  [0, 32768)      : phase 1 = x tile bf16 [64][256], byte ^= (row&7)<<4
//                    phase 2 = Wz staged f32[2048], wz[i] = W[256+i-1] (i>=1)
//  [32768, 163840) : XA bf16 [row 0..63][pos 0..1023], pos = split_id+1, pos 0 = x.Wx
//                    within-row byte ^= ((row>>2)&3)<<3
constexpr int XA_OFF    = 32768;
constexpr int LDS_BYTES = XA_OFF + BM * 2048;           // 163840
constexpr size_t WS_NEED = (size_t)NCOL * DIM * 2;      // 512 KiB bf16 fragment buffer

extern __shared__ char smem[];

__device__ __forceinline__ short f2bf(float f) {
  unsigned x = __builtin_bit_cast(unsigned, f);
  x += 0x7fffu + ((x >> 16) & 1u);            // RNE
  return (short)(x >> 16);
}
__device__ __forceinline__ float bfraw(unsigned hw16) {
  return __builtin_bit_cast(float, hw16 << 16);
}
__device__ __forceinline__ unsigned cvt_pk(float lo, float hi) {
  unsigned r;
  asm("v_cvt_pk_bf16_f32 %0, %1, %2" : "=v"(r) : "v"(lo), "v"(hi));
  return r;
}
__device__ __forceinline__ float clamp01(float v) {
  return fminf(fmaxf(v, 0.f), 1.f);
}

// ---------------- prep: A (f32) + W row -> bf16 MFMA-fragment layout in d_ws ------------
// u32x4 index = ct*512 + ks*64 + lane
// holds A[col = ct*16 + (lane&15)][k = ks*32 + (lane>>4)*8 .. +8)  (col 1023 -> W[0:256))
__global__ void prep_frag(const float* __restrict__ A, const float* __restrict__ W,
                          u32x4* __restrict__ wsf)
{
  int t    = blockIdx.x * 512 + threadIdx.x;      // 0..32767
  int lane = t & 63;
  int ks   = (t >> 6) & 7;
  int ct   = t >> 9;
  int col  = ct * 16 + (lane & 15);
  int k0   = ks * 32 + ((lane >> 4) << 3);
  const float* src = (col < NSPLIT) ? (A + col * DIM + k0) : (W + k0);
  float4_t a0 = *(const float4_t*)src;
  float4_t a1 = *(const float4_t*)(src + 4);
  u32x4 p;
  p[0] = cvt_pk(a0[0], a0[1]);
  p[1] = cvt_pk(a0[2], a0[3]);
  p[2] = cvt_pk(a1[0], a1[1]);
  p[3] = cvt_pk(a1[2], a1[3]);
  wsf[t] = p;
}

// ---------------- B-fragment load (one col-tile, all 8 k-steps) ----------------
template<bool USE_WS>
__device__ __forceinline__ void load_bfr(int pass, bf16x8* dst, int wave, int lane,
                                         const u32x4* __restrict__ wsf,
                                         const float* __restrict__ A,
                                         const float* __restrict__ W)
{
  int ct = pass * 8 + wave;
  if constexpr (USE_WS) {
    const u32x4* fp = wsf + ct * 512 + lane;
#pragma unroll
    for (int ks = 0; ks < 8; ++ks)
      dst[ks] = __builtin_bit_cast(bf16x8, fp[ks * 64]);
  } else {
    int col = ct * 16 + (lane & 15);
    int k0  = (lane >> 4) << 3;
    const float* ap = (col < NSPLIT) ? (A + col * DIM) : W;
#pragma unroll
    for (int ks = 0; ks < 8; ++ks) {
      float4_t a0 = *(const float4_t*)(ap + ks * 32 + k0);
      float4_t a1 = *(const float4_t*)(ap + ks * 32 + k0 + 4);
      u32x4 p;
      p[0] = cvt_pk(a0[0], a0[1]);
      p[1] = cvt_pk(a0[2], a0[3]);
      p[2] = cvt_pk(a1[0], a1[1]);
      p[3] = cvt_pk(a1[2], a1[3]);
      dst[ks] = __builtin_bit_cast(bf16x8, p);
    }
  }
}

// ---------------- fused main kernel ----------------
template<bool USE_WS>
__global__ __launch_bounds__(NTHREADS, 2)
void lt_main(const float* __restrict__ X, const float* __restrict__ A,
             const float* __restrict__ W, const float* __restrict__ Bv,
             const u32x4* __restrict__ wsf, float* __restrict__ Out)
{
  const int tid  = threadIdx.x;
  const int lane = tid & 63;
  const int wave = tid >> 6;
  const int m0   = blockIdx.x * BM;

  // ---- stage x tile: f32 global -> bf16 LDS [64][256], byte ^= (row&7)<<4 ----
  for (int idx = tid; idx < BM * DIM; idx += NTHREADS) {
    int row = idx >> 8, col = idx & 255;
    float v = (col < INSZ) ? X[(m0 + row) * INSZ + col] : 1.0f;
    *(short*)(smem + (((row << 9) + (col << 1)) ^ ((row & 7) << 4))) = f2bf(v);
  }
  __syncthreads();

  // ---- preload x fragments: all 4 M-tiles x 8 K-steps ----
  bf16x8 xf[4][8];
#pragma unroll
  for (int mt = 0; mt < 4; ++mt) {
    int row = mt * 16 + (lane & 15);
#pragma unroll
    for (int ks = 0; ks < 8; ++ks) {
      int kk = ks * 32 + ((lane >> 4) << 3);
      xf[mt][ks] = *(const bf16x8*)(smem + (((row << 9) + (kk << 1)) ^ ((row & 7) << 4)));
    }
  }

  // ---- phase 1: 8 passes; wave owns col-tile ct = pass*8 + wave (all 4 M-tiles) ----
  bf16x8 b0[8], b1[8];
  load_bfr<USE_WS>(0, b0, wave, lane, wsf, A, W);
#pragma unroll
  for (int p = 0; p < 8; ++p) {
    bf16x8* cur = (p & 1) ? b1 : b0;
    bf16x8* nxt = (p & 1) ? b0 : b1;
    if (p < 7) load_bfr<USE_WS>(p + 1, nxt, wave, lane, wsf, A, W);   // prefetch next tile

    f32x4 acc[4];
#pragma unroll
    for (int mt = 0; mt < 4; ++mt) acc[mt] = f32x4{0.f, 0.f, 0.f, 0.f};
#pragma unroll
    for (int ks = 0; ks < 8; ++ks) {
#pragma unroll
      for (int mt = 0; mt < 4; ++mt)
        acc[mt] = __builtin_amdgcn_mfma_f32_16x16x32_bf16(xf[mt][ks], cur[ks], acc[mt], 0, 0, 0);
    }

    // write XA (round-1 verified layout): row-major [sample][pos], pos = col+1, W col -> pos 0
    int col = (p * 8 + wave) * 16 + (lane & 15);
    int pos = (col < NSPLIT) ? (col + 1) : 0;
#pragma unroll
    for (int mt = 0; mt < 4; ++mt) {
#pragma unroll
      for (int j = 0; j < 4; ++j) {
        int row = mt * 16 + ((lane >> 4) << 2) + j;
        int byt = XA_OFF + (row << 11) + (((pos << 1)) ^ (((row >> 2) & 3) << 3));
        *(short*)(smem + byt) = f2bf(acc[mt][j]);
      }
    }
  }
  __syncthreads();

  // ---- stage Wz (shifted by +1 for alignment) into dead x-tile region ----
  for (int i = tid; i < 2048; i += NTHREADS) {
    float w = (i > 0) ? W[DIM + i - 1] : 0.f;
    *(float*)(smem + (i << 2)) = w;
  }
  __syncthreads();

  // ---- phase 2 (round-1 verified): 8 samples per wave ----
  const float bias = Bv[0] + W[DIM];   // b + root node (z0 = 1) * Wz[0]
  const float* wz  = (const float*)smem;

  for (int t = 0; t < 8; ++t) {
    int r = wave * 8 + t;
    const char* xar = smem + XA_OFF + (r << 11);
    const int   swz = ((r >> 2) & 3) << 3;

    float acc = 0.f;
    float q   = 1.0f;
    // levels 1..6: one node per lane (i = lane), parent q via shuffle
#pragma unroll
    for (int l = 1; l <= 6; ++l) {
      float qp = __shfl(q, lane >> 1, 64);
      int  pos = (1 << (l - 1)) + (lane >> 1);           // split_id + 1
      unsigned hw = *(const unsigned short*)(xar + (((pos << 1)) ^ swz));
      float xa = bfraw(hw);
      float e  = (lane & 1) ? -xa : xa;
      q = fminf(qp, e);
      if (lane < (1 << l))
        acc += clamp01(q) * wz[(1 << l) + lane];
    }
    // level 7: i = 2*lane + {0,1}; parent split id 63+lane -> pos 64+lane
    unsigned h7 = *(const unsigned short*)(xar + ((((64 + lane) << 1)) ^ swz));
    float xa7 = bfraw(h7);
    float q7a = fminf(q, xa7), q7b = fminf(q, -xa7);
    acc += clamp01(q7a) * wz[128 + 2 * lane]
         + clamp01(q7b) * wz[128 + 2 * lane + 1];
    // level 8: i = 4*lane + c; xa pos 128+2*lane+{0,1}
    unsigned u8 = *(const unsigned*)(xar + (((256 + 4 * lane)) ^ swz));
    float x8a = bfraw(u8 & 0xffffu), x8b = bfraw(u8 >> 16);
    float q8[4];
    q8[0] = fminf(q7a, x8a);  q8[1] = fminf(q7a, -x8a);
    q8[2] = fminf(q7b, x8b);  q8[3] = fminf(q7b, -x8b);
    {
      float4_t w8 = *(const float4_t*)(wz + 256 + 4 * lane);
      acc += clamp01(q8[0]) * w8[0] + clamp01(q8[1]) * w8[1]
           + clamp01(q8[2]) * w8[2] + clamp01(q8[3]) * w8[3];
    }
    // level 9: i = 8*lane + c; xa pos 256+4*lane+{0..3}
    u32x2 u9 = *(const u32x2*)(xar + (((512 + 8 * lane)) ^ swz));
    float x9[4] = { bfraw(u9[0] & 0xffffu), bfraw(u9[0] >> 16),
                    bfraw(u9[1] & 0xffffu), bfraw(u9[1] >> 16) };
    float q9[8];
#pragma unroll
    for (int c = 0; c < 8; ++c)
      q9[c] = fminf(q8[c >> 1], (c & 1) ? -x9[c >> 1] : x9[c >> 1]);
    {
      float4_t w9a = *(const float4_t*)(wz + 512 + 8 * lane);
      float4_t w9b = *(const float4_t*)(wz + 512 + 8 * lane + 4);
#pragma unroll
      for (int c = 0; c < 4; ++c) acc += clamp01(q9[c]) * w9a[c];
#pragma unroll
      for (int c = 0; c < 4; ++c) acc += clamp01(q9[4 + c]) * w9b[c];
    }
    // level 10: i = 16*lane + c; xa pos 512+8*lane+{0..7}
    u32x2 uA = *(const u32x2*)(xar + (((1024 + 16 * lane)) ^ swz));
    u32x2 uB = *(const u32x2*)(xar + (((1024 + 16 * lane + 8)) ^ swz));
    float xA[8] = { bfraw(uA[0] & 0xffffu), bfraw(uA[0] >> 16),
                    bfraw(uA[1] & 0xffffu), bfraw(uA[1] >> 16),
                    bfraw(uB[0] & 0xffffu), bfraw(uB[0] >> 16),
                    bfraw(uB[1] & 0xffffu), bfraw(uB[1] >> 16) };
    {
      float4_t wA0 = *(const float4_t*)(wz + 1024 + 16 * lane);
      float4_t wA1 = *(const float4_t*)(wz + 1024 + 16 * lane + 4);
      float4_t wA2 = *(const float4_t*)(wz + 1024 + 16 * lane + 8);
      float4_t wA3 = *(const float4_t*)(wz + 1024 + 16 * lane + 12);
#pragma unroll
      for (int c = 0; c < 16; ++c) {
        float qv = fminf(q9[c >> 1], (c & 1) ? -xA[c >> 1] : xA[c >> 1]);
        float wv = (c < 4) ? wA0[c] : (c < 8) ? wA1[c - 4] : (c < 12) ? wA2[c - 8] : wA3[c - 12];
        acc += clamp01(qv) * wv;
      }
    }
    // x . Wx was computed by MFMA into pos 0
    float xw = bfraw(*(const unsigned short*)(xar + (0 ^ swz)));
    // wave reduction
#pragma unroll
    for (int o = 32; o > 0; o >>= 1) acc += __shfl_xor(acc, o, 64);
    if (lane == 0)
      Out[m0 + r] = 1.f / (1.f + __expf(-(acc + xw + bias)));
  }
}

extern "C" void kernel_launch(void* const* d_in, const int* in_sizes, int n_in,
                              void* d_out, int out_size, void* d_ws, size_t ws_size,
                              hipStream_t stream) {
  (void)in_sizes; (void)n_in; (void)out_size;
  const float* X  = (const float*)d_in[0];
  const float* A  = (const float*)d_in[1];
  const float* W  = (const float*)d_in[2];
  const float* Bv = (const float*)d_in[3];
  float* Out = (float*)d_out;

  const bool use_ws = (d_ws != nullptr) && (ws_size >= WS_NEED);
  if (use_ws) {
    prep_frag<<<64, 512, 0, stream>>>(A, W, (u32x4*)d_ws);
    hipFuncSetAttribute(reinterpret_cast<const void*>(lt_main<true>),
                        hipFuncAttributeMaxDynamicSharedMemorySize, LDS_BYTES);
    lt_main<true><<<NSAMP / BM, NTHREADS, LDS_BYTES, stream>>>(
        X, A, W, Bv, (const u32x4*)d_ws, Out);
  } else {
    hipFuncSetAttribute(reinterpret_cast<const void*>(lt_main<false>),
                        hipFuncAttributeMaxDynamicSharedMemorySize, LDS_BYTES);
    lt_main<false><<<NSAMP / BM, NTHREADS, LDS_BYTES, stream>>>(
        X, A, W, Bv, nullptr, Out);
  }
}

// Round 4
// 60.275 us; speedup vs baseline: 2.7151x; 1.2545x over previous
//
#include <hip/hip_runtime.h>

typedef __attribute__((ext_vector_type(8))) short    bf16x8;
typedef __attribute__((ext_vector_type(4))) float    f32x4;
typedef __attribute__((ext_vector_type(4))) float    float4_t;
typedef __attribute__((ext_vector_type(4))) unsigned u32x4;
typedef __attribute__((ext_vector_type(2))) unsigned u32x2;

constexpr int NSAMP    = 32768;
constexpr int INSZ     = 255;
constexpr int DIM      = 256;      // IN_SIZE + bias
constexpr int NSPLIT   = 1023;
constexpr int NCOL     = 1024;     // 1023 split cols + W as col 1023
constexpr int BM       = 64;       // samples per block
constexpr int NTHREADS = 512;      // 8 waves

// LDS layout:
//  [0, 32768)      : phase 1 = x tile bf16 [64][256], byte ^= (row&7)<<4
//                    phase 2 = Wz f32[2048] at [0,8K) ; part f32[64][68] at [8K, ~25.6K)
//  [32768, 163840) : XA bf16 [row 0..63][pos 0..1023], pos = split_id+1, pos 0 = x.Wx
//                    within-row byte ^= ((row>>2)&3)<<3
constexpr int XA_OFF    = 32768;
constexpr int PART_OFF  = 8192;
constexpr int PSTRIDE   = 68;                           // floats; breaks 256B row-stride banks
constexpr int LDS_BYTES = XA_OFF + BM * 2048;           // 163840
constexpr size_t WS_NEED = (size_t)NCOL * DIM * 2;      // 512 KiB bf16 fragment buffer

extern __shared__ char smem[];

__device__ __forceinline__ short f2bf(float f) {
  unsigned x = __builtin_bit_cast(unsigned, f);
  x += 0x7fffu + ((x >> 16) & 1u);            // RNE
  return (short)(x >> 16);
}
__device__ __forceinline__ float bfraw(unsigned hw16) {
  return __builtin_bit_cast(float, hw16 << 16);
}
__device__ __forceinline__ unsigned cvt_pk(float lo, float hi) {
  unsigned r;
  asm("v_cvt_pk_bf16_f32 %0, %1, %2" : "=v"(r) : "v"(lo), "v"(hi));
  return r;
}
__device__ __forceinline__ float clamp01(float v) {
  return fminf(fmaxf(v, 0.f), 1.f);
}

// ---------------- prep: A (f32) + W row -> bf16 MFMA-fragment layout in d_ws ------------
// u32x4 index = ct*512 + ks*64 + lane
// holds A[col = ct*16 + (lane&15)][k = ks*32 + (lane>>4)*8 .. +8)  (col 1023 -> W[0:256))
__global__ void prep_frag(const float* __restrict__ A, const float* __restrict__ W,
                          u32x4* __restrict__ wsf)
{
  int t    = blockIdx.x * 512 + threadIdx.x;      // 0..32767
  int lane = t & 63;
  int ks   = (t >> 6) & 7;
  int ct   = t >> 9;
  int col  = ct * 16 + (lane & 15);
  int k0   = ks * 32 + ((lane >> 4) << 3);
  const float* src = (col < NSPLIT) ? (A + col * DIM + k0) : (W + k0);
  float4_t a0 = *(const float4_t*)src;
  float4_t a1 = *(const float4_t*)(src + 4);
  u32x4 p;
  p[0] = cvt_pk(a0[0], a0[1]);
  p[1] = cvt_pk(a0[2], a0[3]);
  p[2] = cvt_pk(a1[0], a1[1]);
  p[3] = cvt_pk(a1[2], a1[3]);
  wsf[t] = p;
}

// ---------------- B-fragment load (one col-tile, all 8 k-steps) ----------------
template<bool USE_WS>
__device__ __forceinline__ void load_bfr(int pass, bf16x8* dst, int wave, int lane,
                                         const u32x4* __restrict__ wsf,
                                         const float* __restrict__ A,
                                         const float* __restrict__ W)
{
  int ct = pass * 8 + wave;
  if constexpr (USE_WS) {
    const u32x4* fp = wsf + ct * 512 + lane;
#pragma unroll
    for (int ks = 0; ks < 8; ++ks)
      dst[ks] = __builtin_bit_cast(bf16x8, fp[ks * 64]);
  } else {
    int col = ct * 16 + (lane & 15);
    int k0  = (lane >> 4) << 3;
    const float* ap = (col < NSPLIT) ? (A + col * DIM) : W;
#pragma unroll
    for (int ks = 0; ks < 8; ++ks) {
      float4_t a0 = *(const float4_t*)(ap + ks * 32 + k0);
      float4_t a1 = *(const float4_t*)(ap + ks * 32 + k0 + 4);
      u32x4 p;
      p[0] = cvt_pk(a0[0], a0[1]);
      p[1] = cvt_pk(a0[2], a0[3]);
      p[2] = cvt_pk(a1[0], a1[1]);
      p[3] = cvt_pk(a1[2], a1[3]);
      dst[ks] = __builtin_bit_cast(bf16x8, p);
    }
  }
}

// ---------------- per-sample tree walk (round-1-verified math) ----------------
// lane-parallel over nodes; returns this lane's partial of sum_i clip(q_i)*Wz_i
__device__ __forceinline__ float walk(const char* __restrict__ xar, int swz,
                                      const float* __restrict__ wz, int lane)
{
  float acc = 0.f;
  float q   = 1.0f;
  // levels 1..6: one node per lane (i = lane), parent q via shuffle
#pragma unroll
  for (int l = 1; l <= 6; ++l) {
    float qp = __shfl(q, lane >> 1, 64);
    int  pos = (1 << (l - 1)) + (lane >> 1);           // split_id + 1
    unsigned hw = *(const unsigned short*)(xar + (((pos << 1)) ^ swz));
    float xa = bfraw(hw);
    float e  = (lane & 1) ? -xa : xa;
    q = fminf(qp, e);
    if (lane < (1 << l))
      acc += clamp01(q) * wz[(1 << l) + lane];
  }
  // level 7: i = 2*lane + {0,1}; parent split id 63+lane -> pos 64+lane
  unsigned h7 = *(const unsigned short*)(xar + ((((64 + lane) << 1)) ^ swz));
  float xa7 = bfraw(h7);
  float q7a = fminf(q, xa7), q7b = fminf(q, -xa7);
  acc += clamp01(q7a) * wz[128 + 2 * lane]
       + clamp01(q7b) * wz[128 + 2 * lane + 1];
  // level 8: i = 4*lane + c; xa pos 128+2*lane+{0,1}
  unsigned u8 = *(const unsigned*)(xar + (((256 + 4 * lane)) ^ swz));
  float x8a = bfraw(u8 & 0xffffu), x8b = bfraw(u8 >> 16);
  float q8[4];
  q8[0] = fminf(q7a, x8a);  q8[1] = fminf(q7a, -x8a);
  q8[2] = fminf(q7b, x8b);  q8[3] = fminf(q7b, -x8b);
  {
    float4_t w8 = *(const float4_t*)(wz + 256 + 4 * lane);
    acc += clamp01(q8[0]) * w8[0] + clamp01(q8[1]) * w8[1]
         + clamp01(q8[2]) * w8[2] + clamp01(q8[3]) * w8[3];
  }
  // level 9: i = 8*lane + c; xa pos 256+4*lane+{0..3}
  u32x2 u9 = *(const u32x2*)(xar + (((512 + 8 * lane)) ^ swz));
  float x9[4] = { bfraw(u9[0] & 0xffffu), bfraw(u9[0] >> 16),
                  bfraw(u9[1] & 0xffffu), bfraw(u9[1] >> 16) };
  float q9[8];
#pragma unroll
  for (int c = 0; c < 8; ++c)
    q9[c] = fminf(q8[c >> 1], (c & 1) ? -x9[c >> 1] : x9[c >> 1]);
  {
    float4_t w9a = *(const float4_t*)(wz + 512 + 8 * lane);
    float4_t w9b = *(const float4_t*)(wz + 512 + 8 * lane + 4);
#pragma unroll
    for (int c = 0; c < 4; ++c) acc += clamp01(q9[c]) * w9a[c];
#pragma unroll
    for (int c = 0; c < 4; ++c) acc += clamp01(q9[4 + c]) * w9b[c];
  }
  // level 10: i = 16*lane + c; xa pos 512+8*lane+{0..7}
  u32x2 uA = *(const u32x2*)(xar + (((1024 + 16 * lane)) ^ swz));
  u32x2 uB = *(const u32x2*)(xar + (((1024 + 16 * lane + 8)) ^ swz));
  float xA[8] = { bfraw(uA[0] & 0xffffu), bfraw(uA[0] >> 16),
                  bfraw(uA[1] & 0xffffu), bfraw(uA[1] >> 16),
                  bfraw(uB[0] & 0xffffu), bfraw(uB[0] >> 16),
                  bfraw(uB[1] & 0xffffu), bfraw(uB[1] >> 16) };
  {
    float4_t wA0 = *(const float4_t*)(wz + 1024 + 16 * lane);
    float4_t wA1 = *(const float4_t*)(wz + 1024 + 16 * lane + 4);
    float4_t wA2 = *(const float4_t*)(wz + 1024 + 16 * lane + 8);
    float4_t wA3 = *(const float4_t*)(wz + 1024 + 16 * lane + 12);
#pragma unroll
    for (int c = 0; c < 16; ++c) {
      float qv = fminf(q9[c >> 1], (c & 1) ? -xA[c >> 1] : xA[c >> 1]);
      float wv = (c < 4) ? wA0[c] : (c < 8) ? wA1[c - 4] : (c < 12) ? wA2[c - 8] : wA3[c - 12];
      acc += clamp01(qv) * wv;
    }
  }
  return acc;
}

// ---------------- fused main kernel ----------------
template<bool USE_WS>
__global__ __launch_bounds__(NTHREADS) __attribute__((amdgpu_waves_per_eu(2)))
void lt_main(const float* __restrict__ X, const float* __restrict__ A,
             const float* __restrict__ W, const float* __restrict__ Bv,
             const u32x4* __restrict__ wsf, float* __restrict__ Out)
{
  const int tid  = threadIdx.x;
  const int lane = tid & 63;
  const int wave = tid >> 6;
  const int m0   = blockIdx.x * BM;

  // ---- issue pass-0 B fragments early (L2 latency overlaps X staging) ----
  bf16x8 b0[8], b1[8];
  load_bfr<USE_WS>(0, b0, wave, lane, wsf, A, W);

  // ---- stage x tile: contiguous 64*255 f32 region, float4 loads ----
  {
    const float4_t* Xt = (const float4_t*)(X + (size_t)m0 * INSZ);
#pragma unroll
    for (int i = 0; i < 8; ++i) {
      int idx = tid + i * NTHREADS;
      if (idx < 4080) {                      // 64*255/4
        float4_t v = Xt[idx];
#pragma unroll
        for (int e = 0; e < 4; ++e) {
          int g   = idx * 4 + e;
          int row = g / 255;
          int col = g - row * 255;
          *(short*)(smem + (((row << 9) + (col << 1)) ^ ((row & 7) << 4))) = f2bf(v[e]);
        }
      }
    }
    if (tid < BM)                            // bias column (=1.0)
      *(short*)(smem + (((tid << 9) + (255 << 1)) ^ ((tid & 7) << 4))) = (short)0x3f80;
  }
  __syncthreads();

  // ---- preload x fragments: all 4 M-tiles x 8 K-steps (128 VGPR, no spill now) ----
  bf16x8 xf[4][8];
#pragma unroll
  for (int mt = 0; mt < 4; ++mt) {
    int row = mt * 16 + (lane & 15);
#pragma unroll
    for (int ks = 0; ks < 8; ++ks) {
      int kk = ks * 32 + ((lane >> 4) << 3);
      xf[mt][ks] = *(const bf16x8*)(smem + (((row << 9) + (kk << 1)) ^ ((row & 7) << 4)));
    }
  }

  // ---- phase 1: 8 passes; wave owns col-tile ct = pass*8 + wave (all 4 M-tiles) ----
#pragma unroll
  for (int p = 0; p < 8; ++p) {
    bf16x8* cur = (p & 1) ? b1 : b0;
    bf16x8* nxt = (p & 1) ? b0 : b1;
    if (p < 7) load_bfr<USE_WS>(p + 1, nxt, wave, lane, wsf, A, W);   // prefetch next tile

    f32x4 acc[4];
#pragma unroll
    for (int mt = 0; mt < 4; ++mt) acc[mt] = f32x4{0.f, 0.f, 0.f, 0.f};
#pragma unroll
    for (int ks = 0; ks < 8; ++ks) {
#pragma unroll
      for (int mt = 0; mt < 4; ++mt)
        acc[mt] = __builtin_amdgcn_mfma_f32_16x16x32_bf16(xf[mt][ks], cur[ks], acc[mt], 0, 0, 0);
    }

    // write XA: row-major [sample][pos], pos = col+1, W col -> pos 0
    int col = (p * 8 + wave) * 16 + (lane & 15);
    int pos = (col < NSPLIT) ? (col + 1) : 0;
#pragma unroll
    for (int mt = 0; mt < 4; ++mt) {
#pragma unroll
      for (int j = 0; j < 4; ++j) {
        int row = mt * 16 + ((lane >> 4) << 2) + j;
        int byt = XA_OFF + (row << 11) + (((pos << 1)) ^ (((row >> 2) & 3) << 3));
        *(short*)(smem + byt) = f2bf(acc[mt][j]);
      }
    }
  }
  __syncthreads();

  // ---- stage Wz (shifted by +1 for alignment) into dead x-tile region ----
  for (int i = tid; i < 2048; i += NTHREADS) {
    float w = (i > 0) ? W[DIM + i - 1] : 0.f;
    *(float*)(smem + (i << 2)) = w;
  }
  __syncthreads();

  // ---- phase 2: 8 samples per wave, 2 at a time for ILP ----
  const float* wz   = (const float*)smem;
  float*       part = (float*)(smem + PART_OFF);

#pragma unroll
  for (int t = 0; t < 4; ++t) {
    int rA = wave * 8 + 2 * t;
    int rB = rA + 1;
    const char* xarA = smem + XA_OFF + (rA << 11);
    const char* xarB = smem + XA_OFF + (rB << 11);
    const int swzA = ((rA >> 2) & 3) << 3;
    const int swzB = ((rB >> 2) & 3) << 3;
    float accA = walk(xarA, swzA, wz, lane);
    float accB = walk(xarB, swzB, wz, lane);
    part[rA * PSTRIDE + lane] = accA;
    part[rB * PSTRIDE + lane] = accB;
  }
  __syncthreads();

  // ---- final reduction: 8 lanes per sample ----
  {
    int r = tid >> 3, j = tid & 7;           // 512 threads -> 64 samples
    const float* pr = part + r * PSTRIDE + j * 8;
    float4_t s0 = *(const float4_t*)pr;
    float4_t s1 = *(const float4_t*)(pr + 4);
    float sum = ((s0[0] + s0[1]) + (s0[2] + s0[3]))
              + ((s1[0] + s1[1]) + (s1[2] + s1[3]));
    sum += __shfl_xor(sum, 1, 64);
    sum += __shfl_xor(sum, 2, 64);
    sum += __shfl_xor(sum, 4, 64);
    if (j == 0) {
      const char* xar = smem + XA_OFF + (r << 11);
      int swz = ((r >> 2) & 3) << 3;
      float xw = bfraw(*(const unsigned short*)(xar + (0 ^ swz)));   // x.Wx from MFMA col
      float bias = Bv[0] + W[DIM];           // b + root weight (z_root = 1)
      Out[m0 + r] = 1.f / (1.f + __expf(-(sum + xw + bias)));
    }
  }
}

extern "C" void kernel_launch(void* const* d_in, const int* in_sizes, int n_in,
                              void* d_out, int out_size, void* d_ws, size_t ws_size,
                              hipStream_t stream) {
  (void)in_sizes; (void)n_in; (void)out_size;
  const float* X  = (const float*)d_in[0];
  const float* A  = (const float*)d_in[1];
  const float* W  = (const float*)d_in[2];
  const float* Bv = (const float*)d_in[3];
  float* Out = (float*)d_out;

  const bool use_ws = (d_ws != nullptr) && (ws_size >= WS_NEED);
  if (use_ws) {
    prep_frag<<<64, 512, 0, stream>>>(A, W, (u32x4*)d_ws);
    hipFuncSetAttribute(reinterpret_cast<const void*>(lt_main<true>),
                        hipFuncAttributeMaxDynamicSharedMemorySize, LDS_BYTES);
    lt_main<true><<<NSAMP / BM, NTHREADS, LDS_BYTES, stream>>>(
        X, A, W, Bv, (const u32x4*)d_ws, Out);
  } else {
    hipFuncSetAttribute(reinterpret_cast<const void*>(lt_main<false>),
                        hipFuncAttributeMaxDynamicSharedMemorySize, LDS_BYTES);
    lt_main<false><<<NSAMP / BM, NTHREADS, LDS_BYTES, stream>>>(
        X, A, W, Bv, nullptr, Out);
  }
}

// Round 5
// 45.631 us; speedup vs baseline: 3.5864x; 1.3209x over previous
//
#include <hip/hip_runtime.h>

typedef __attribute__((ext_vector_type(8))) short    bf16x8;
typedef __attribute__((ext_vector_type(4))) float    f32x4;
typedef __attribute__((ext_vector_type(4))) float    float4_t;
typedef __attribute__((ext_vector_type(4))) unsigned u32x4;
typedef __attribute__((ext_vector_type(2))) unsigned u32x2;

constexpr int NSAMP    = 32768;
constexpr int INSZ     = 255;
constexpr int DIM      = 256;      // IN_SIZE + bias
constexpr int NSPLIT   = 1023;
constexpr int NCOL     = 1024;     // 1023 split cols + W as col 1023
constexpr int BM       = 64;       // samples per block
constexpr int NTHREADS = 512;      // 8 waves

// LDS layout:
//  [0, 32768)      : phase 1 = x tile bf16 [64][256], byte ^= (row&7)<<4
//                    phase 2 = Wz f32[2048] at [0,8K) ; part f32[64][68] at [8K, ~25.6K)
//  [32768, 163840) : XA bf16 [row 0..63][pos 0..1023], pos = split_id+1, pos 0 = x.Wx
//                    within-row byte ^= ((row>>2)&3)<<3
constexpr int XA_OFF    = 32768;
constexpr int PART_OFF  = 8192;
constexpr int PSTRIDE   = 68;                           // floats; breaks 256B row-stride banks
constexpr int LDS_BYTES = XA_OFF + BM * 2048;           // 163840
constexpr size_t WS_NEED = (size_t)NCOL * DIM * 2;      // 512 KiB bf16 fragment buffer

extern __shared__ char smem[];

__device__ __forceinline__ short f2bf(float f) {
  unsigned x = __builtin_bit_cast(unsigned, f);
  x += 0x7fffu + ((x >> 16) & 1u);            // RNE
  return (short)(x >> 16);
}
__device__ __forceinline__ float bfraw(unsigned hw16) {
  return __builtin_bit_cast(float, hw16 << 16);
}
__device__ __forceinline__ unsigned cvt_pk(float lo, float hi) {
  unsigned r;
  asm("v_cvt_pk_bf16_f32 %0, %1, %2" : "=v"(r) : "v"(lo), "v"(hi));
  return r;
}
__device__ __forceinline__ float clamp01(float v) {
  return fminf(fmaxf(v, 0.f), 1.f);
}

// ---------------- prep: A (f32) + W row -> bf16 MFMA-fragment layout in d_ws ------------
// u32x4 index = ct*512 + ks*64 + lane
// holds A[col = ct*16 + (lane&15)][k = ks*32 + (lane>>4)*8 .. +8)  (col 1023 -> W[0:256))
__global__ void prep_frag(const float* __restrict__ A, const float* __restrict__ W,
                          u32x4* __restrict__ wsf)
{
  int t    = blockIdx.x * 512 + threadIdx.x;      // 0..32767
  int lane = t & 63;
  int ks   = (t >> 6) & 7;
  int ct   = t >> 9;
  int col  = ct * 16 + (lane & 15);
  int k0   = ks * 32 + ((lane >> 4) << 3);
  const float* src = (col < NSPLIT) ? (A + col * DIM + k0) : (W + k0);
  float4_t a0 = *(const float4_t*)src;
  float4_t a1 = *(const float4_t*)(src + 4);
  u32x4 p;
  p[0] = cvt_pk(a0[0], a0[1]);
  p[1] = cvt_pk(a0[2], a0[3]);
  p[2] = cvt_pk(a1[0], a1[1]);
  p[3] = cvt_pk(a1[2], a1[3]);
  wsf[t] = p;
}

// ---------------- B-fragment load (one col-tile, all 8 k-steps) ----------------
template<bool USE_WS>
__device__ __forceinline__ void load_bfr(int pass, bf16x8* dst, int wave, int lane,
                                         const u32x4* __restrict__ wsf,
                                         const float* __restrict__ A,
                                         const float* __restrict__ W)
{
  int ct = pass * 8 + wave;
  if constexpr (USE_WS) {
    const u32x4* fp = wsf + ct * 512 + lane;
#pragma unroll
    for (int ks = 0; ks < 8; ++ks)
      dst[ks] = __builtin_bit_cast(bf16x8, fp[ks * 64]);
  } else {
    int col = ct * 16 + (lane & 15);
    int k0  = (lane >> 4) << 3;
    const float* ap = (col < NSPLIT) ? (A + col * DIM) : W;
#pragma unroll
    for (int ks = 0; ks < 8; ++ks) {
      float4_t a0 = *(const float4_t*)(ap + ks * 32 + k0);
      float4_t a1 = *(const float4_t*)(ap + ks * 32 + k0 + 4);
      u32x4 p;
      p[0] = cvt_pk(a0[0], a0[1]);
      p[1] = cvt_pk(a0[2], a0[3]);
      p[2] = cvt_pk(a1[0], a1[1]);
      p[3] = cvt_pk(a1[2], a1[3]);
      dst[ks] = __builtin_bit_cast(bf16x8, p);
    }
  }
}

// ---------------- per-sample tree walk (round-1-verified math) ----------------
// lane-parallel over nodes; returns this lane's partial of sum_i clip(q_i)*Wz_i
__device__ __forceinline__ float walk(const char* __restrict__ xar, int swz,
                                      const float* __restrict__ wz, int lane)
{
  float acc = 0.f;
  float q   = 1.0f;
  // levels 1..6: one node per lane (i = lane), parent q via shuffle
#pragma unroll
  for (int l = 1; l <= 6; ++l) {
    float qp = __shfl(q, lane >> 1, 64);
    int  pos = (1 << (l - 1)) + (lane >> 1);           // split_id + 1
    unsigned hw = *(const unsigned short*)(xar + (((pos << 1)) ^ swz));
    float xa = bfraw(hw);
    float e  = (lane & 1) ? -xa : xa;
    q = fminf(qp, e);
    if (lane < (1 << l))
      acc += clamp01(q) * wz[(1 << l) + lane];
  }
  // level 7: i = 2*lane + {0,1}; parent split id 63+lane -> pos 64+lane
  unsigned h7 = *(const unsigned short*)(xar + ((((64 + lane) << 1)) ^ swz));
  float xa7 = bfraw(h7);
  float q7a = fminf(q, xa7), q7b = fminf(q, -xa7);
  acc += clamp01(q7a) * wz[128 + 2 * lane]
       + clamp01(q7b) * wz[128 + 2 * lane + 1];
  // level 8: i = 4*lane + c; xa pos 128+2*lane+{0,1}
  unsigned u8 = *(const unsigned*)(xar + (((256 + 4 * lane)) ^ swz));
  float x8a = bfraw(u8 & 0xffffu), x8b = bfraw(u8 >> 16);
  float q8[4];
  q8[0] = fminf(q7a, x8a);  q8[1] = fminf(q7a, -x8a);
  q8[2] = fminf(q7b, x8b);  q8[3] = fminf(q7b, -x8b);
  {
    float4_t w8 = *(const float4_t*)(wz + 256 + 4 * lane);
    acc += clamp01(q8[0]) * w8[0] + clamp01(q8[1]) * w8[1]
         + clamp01(q8[2]) * w8[2] + clamp01(q8[3]) * w8[3];
  }
  // level 9: i = 8*lane + c; xa pos 256+4*lane+{0..3}
  u32x2 u9 = *(const u32x2*)(xar + (((512 + 8 * lane)) ^ swz));
  float x9[4] = { bfraw(u9[0] & 0xffffu), bfraw(u9[0] >> 16),
                  bfraw(u9[1] & 0xffffu), bfraw(u9[1] >> 16) };
  float q9[8];
#pragma unroll
  for (int c = 0; c < 8; ++c)
    q9[c] = fminf(q8[c >> 1], (c & 1) ? -x9[c >> 1] : x9[c >> 1]);
  {
    float4_t w9a = *(const float4_t*)(wz + 512 + 8 * lane);
    float4_t w9b = *(const float4_t*)(wz + 512 + 8 * lane + 4);
#pragma unroll
    for (int c = 0; c < 4; ++c) acc += clamp01(q9[c]) * w9a[c];
#pragma unroll
    for (int c = 0; c < 4; ++c) acc += clamp01(q9[4 + c]) * w9b[c];
  }
  // level 10: i = 16*lane + c; xa pos 512+8*lane+{0..7}
  u32x2 uA = *(const u32x2*)(xar + (((1024 + 16 * lane)) ^ swz));
  u32x2 uB = *(const u32x2*)(xar + (((1024 + 16 * lane + 8)) ^ swz));
  float xA[8] = { bfraw(uA[0] & 0xffffu), bfraw(uA[0] >> 16),
                  bfraw(uA[1] & 0xffffu), bfraw(uA[1] >> 16),
                  bfraw(uB[0] & 0xffffu), bfraw(uB[0] >> 16),
                  bfraw(uB[1] & 0xffffu), bfraw(uB[1] >> 16) };
  {
    float4_t wA0 = *(const float4_t*)(wz + 1024 + 16 * lane);
    float4_t wA1 = *(const float4_t*)(wz + 1024 + 16 * lane + 4);
    float4_t wA2 = *(const float4_t*)(wz + 1024 + 16 * lane + 8);
    float4_t wA3 = *(const float4_t*)(wz + 1024 + 16 * lane + 12);
#pragma unroll
    for (int c = 0; c < 16; ++c) {
      float qv = fminf(q9[c >> 1], (c & 1) ? -xA[c >> 1] : xA[c >> 1]);
      float wv = (c < 4) ? wA0[c] : (c < 8) ? wA1[c - 4] : (c < 12) ? wA2[c - 8] : wA3[c - 12];
      acc += clamp01(qv) * wv;
    }
  }
  return acc;
}

// ---------------- fused main kernel ----------------
// LDS (160 KiB) caps us at 1 block/CU = 2 waves/EU regardless; pin the register
// budget to that occupancy so the allocator gets 256 VGPRs (live set ~230).
template<bool USE_WS>
__global__ __launch_bounds__(NTHREADS) __attribute__((amdgpu_waves_per_eu(2, 2)))
void lt_main(const float* __restrict__ X, const float* __restrict__ A,
             const float* __restrict__ W, const float* __restrict__ Bv,
             const u32x4* __restrict__ wsf, float* __restrict__ Out)
{
  const int tid  = threadIdx.x;
  const int lane = tid & 63;
  const int wave = tid >> 6;
  const int m0   = blockIdx.x * BM;

  // ---- issue pass-0 B fragments early (L2 latency overlaps X staging) ----
  bf16x8 b0[8], b1[8];
  load_bfr<USE_WS>(0, b0, wave, lane, wsf, A, W);

  // ---- stage x tile: contiguous 64*255 f32 region, float4 loads ----
  {
    const float4_t* Xt = (const float4_t*)(X + (size_t)m0 * INSZ);
#pragma unroll
    for (int i = 0; i < 8; ++i) {
      int idx = tid + i * NTHREADS;
      if (idx < 4080) {                      // 64*255/4
        float4_t v = Xt[idx];
#pragma unroll
        for (int e = 0; e < 4; ++e) {
          int g   = idx * 4 + e;
          int row = g / 255;
          int col = g - row * 255;
          *(short*)(smem + (((row << 9) + (col << 1)) ^ ((row & 7) << 4))) = f2bf(v[e]);
        }
      }
    }
    if (tid < BM)                            // bias column (=1.0)
      *(short*)(smem + (((tid << 9) + (255 << 1)) ^ ((tid & 7) << 4))) = (short)0x3f80;
  }
  __syncthreads();

  // ---- preload x fragments: all 4 M-tiles x 8 K-steps (128 VGPR, resident) ----
  bf16x8 xf[4][8];
#pragma unroll
  for (int mt = 0; mt < 4; ++mt) {
    int row = mt * 16 + (lane & 15);
#pragma unroll
    for (int ks = 0; ks < 8; ++ks) {
      int kk = ks * 32 + ((lane >> 4) << 3);
      xf[mt][ks] = *(const bf16x8*)(smem + (((row << 9) + (kk << 1)) ^ ((row & 7) << 4)));
    }
  }

  // ---- phase 1: 8 passes; wave owns col-tile ct = pass*8 + wave (all 4 M-tiles) ----
#pragma unroll
  for (int p = 0; p < 8; ++p) {
    bf16x8* cur = (p & 1) ? b1 : b0;
    bf16x8* nxt = (p & 1) ? b0 : b1;
    if (p < 7) load_bfr<USE_WS>(p + 1, nxt, wave, lane, wsf, A, W);   // prefetch next tile

    f32x4 acc[4];
#pragma unroll
    for (int mt = 0; mt < 4; ++mt) acc[mt] = f32x4{0.f, 0.f, 0.f, 0.f};
#pragma unroll
    for (int ks = 0; ks < 8; ++ks) {
#pragma unroll
      for (int mt = 0; mt < 4; ++mt)
        acc[mt] = __builtin_amdgcn_mfma_f32_16x16x32_bf16(xf[mt][ks], cur[ks], acc[mt], 0, 0, 0);
    }

    // write XA: row-major [sample][pos], pos = col+1, W col -> pos 0
    int col = (p * 8 + wave) * 16 + (lane & 15);
    int pos = (col < NSPLIT) ? (col + 1) : 0;
#pragma unroll
    for (int mt = 0; mt < 4; ++mt) {
#pragma unroll
      for (int j = 0; j < 4; ++j) {
        int row = mt * 16 + ((lane >> 4) << 2) + j;
        int byt = XA_OFF + (row << 11) + (((pos << 1)) ^ (((row >> 2) & 3) << 3));
        *(short*)(smem + byt) = f2bf(acc[mt][j]);
      }
    }
  }
  __syncthreads();

  // ---- stage Wz (shifted by +1 for alignment) into dead x-tile region ----
  for (int i = tid; i < 2048; i += NTHREADS) {
    float w = (i > 0) ? W[DIM + i - 1] : 0.f;
    *(float*)(smem + (i << 2)) = w;
  }
  __syncthreads();

  // ---- phase 2: 8 samples per wave, 2 at a time for ILP ----
  const float* wz   = (const float*)smem;
  float*       part = (float*)(smem + PART_OFF);

#pragma unroll
  for (int t = 0; t < 4; ++t) {
    int rA = wave * 8 + 2 * t;
    int rB = rA + 1;
    const char* xarA = smem + XA_OFF + (rA << 11);
    const char* xarB = smem + XA_OFF + (rB << 11);
    const int swzA = ((rA >> 2) & 3) << 3;
    const int swzB = ((rB >> 2) & 3) << 3;
    float accA = walk(xarA, swzA, wz, lane);
    float accB = walk(xarB, swzB, wz, lane);
    part[rA * PSTRIDE + lane] = accA;
    part[rB * PSTRIDE + lane] = accB;
  }
  __syncthreads();

  // ---- final reduction: 8 lanes per sample ----
  {
    int r = tid >> 3, j = tid & 7;           // 512 threads -> 64 samples
    const float* pr = part + r * PSTRIDE + j * 8;
    float4_t s0 = *(const float4_t*)pr;
    float4_t s1 = *(const float4_t*)(pr + 4);
    float sum = ((s0[0] + s0[1]) + (s0[2] + s0[3]))
              + ((s1[0] + s1[1]) + (s1[2] + s1[3]));
    sum += __shfl_xor(sum, 1, 64);
    sum += __shfl_xor(sum, 2, 64);
    sum += __shfl_xor(sum, 4, 64);
    if (j == 0) {
      const char* xar = smem + XA_OFF + (r << 11);
      int swz = ((r >> 2) & 3) << 3;
      float xw = bfraw(*(const unsigned short*)(xar + (0 ^ swz)));   // x.Wx from MFMA col
      float bias = Bv[0] + W[DIM];           // b + root weight (z_root = 1)
      Out[m0 + r] = 1.f / (1.f + __expf(-(sum + xw + bias)));
    }
  }
}

extern "C" void kernel_launch(void* const* d_in, const int* in_sizes, int n_in,
                              void* d_out, int out_size, void* d_ws, size_t ws_size,
                              hipStream_t stream) {
  (void)in_sizes; (void)n_in; (void)out_size;
  const float* X  = (const float*)d_in[0];
  const float* A  = (const float*)d_in[1];
  const float* W  = (const float*)d_in[2];
  const float* Bv = (const float*)d_in[3];
  float* Out = (float*)d_out;

  const bool use_ws = (d_ws != nullptr) && (ws_size >= WS_NEED);
  if (use_ws) {
    prep_frag<<<64, 512, 0, stream>>>(A, W, (u32x4*)d_ws);
    hipFuncSetAttribute(reinterpret_cast<const void*>(lt_main<true>),
                        hipFuncAttributeMaxDynamicSharedMemorySize, LDS_BYTES);
    lt_main<true><<<NSAMP / BM, NTHREADS, LDS_BYTES, stream>>>(
        X, A, W, Bv, (const u32x4*)d_ws, Out);
  } else {
    hipFuncSetAttribute(reinterpret_cast<const void*>(lt_main<false>),
                        hipFuncAttributeMaxDynamicSharedMemorySize, LDS_BYTES);
    lt_main<false><<<NSAMP / BM, NTHREADS, LDS_BYTES, stream>>>(
        X, A, W, Bv, nullptr, Out);
  }
}